// Round 1
// baseline (2724.963 us; speedup 1.0000x reference)
//
#include <hip/hip_runtime.h>

#define NN 50000
#define EE 800000
#define DIM 128
#define OUTC 20
#define LL 7
#define LE (LL*EE)
#define LN (LL*NN)
#define BN_EPS 1e-5f

static __device__ __forceinline__ float sigm(float z){ return 1.0f/(1.0f+expf(-z)); }

// ---------------- preprocessing: counting sort of all 7 edge lists by dst ----------------
__global__ void k_hist(const int* __restrict__ ei, int* __restrict__ cnt){
  int gid = blockIdx.x*256 + threadIdx.x;
  if (gid >= LE) return;
  int l = gid / EE;
  int e = gid - l*EE;
  int dst = ei[(2*l+1)*EE + e];
  atomicAdd(&cnt[l*NN + dst], 1);
}

__global__ void k_scan1(const int* __restrict__ cnt, int* __restrict__ offs,
                        int* __restrict__ bsums, int n){
  __shared__ int s[256];
  int t = threadIdx.x;
  int base = blockIdx.x*1024 + t*4;
  int v[4]; int sum = 0;
  #pragma unroll
  for (int i=0;i<4;i++){ v[i] = (base+i<n)? cnt[base+i] : 0; sum += v[i]; }
  s[t]=sum; __syncthreads();
  for (int off=1; off<256; off<<=1){
    int x = (t>=off)? s[t-off] : 0;
    __syncthreads();
    s[t] += x;
    __syncthreads();
  }
  if (t==255) bsums[blockIdx.x] = s[255];
  int run = s[t]-sum;
  #pragma unroll
  for (int i=0;i<4;i++){ if (base+i<n) offs[base+i]=run; run += v[i]; }
}

__global__ void k_scan2(int* bsums, int nb){
  __shared__ int s[512];
  int t=threadIdx.x;
  int v = (t<nb)? bsums[t]:0;
  s[t]=v; __syncthreads();
  for (int off=1; off<512; off<<=1){
    int x=(t>=off)? s[t-off]:0; __syncthreads(); s[t]+=x; __syncthreads();
  }
  if (t<nb) bsums[t] = s[t]-v;
}

__global__ void k_scan3(int* __restrict__ offs, const int* __restrict__ bsums,
                        int* __restrict__ cursor, int n){
  int gid = blockIdx.x*256+threadIdx.x;
  if (gid < n){
    int val = offs[gid] + bsums[gid>>10];
    offs[gid]=val; cursor[gid]=val;
  }
  if (gid==0) offs[n]=LE;
}

__global__ void k_scatter(const int* __restrict__ ei, const float* __restrict__ ew,
                          int* __restrict__ cursor, int* __restrict__ ssrc,
                          float* __restrict__ sw){
  int gid = blockIdx.x*256+threadIdx.x;
  if (gid>=LE) return;
  int l = gid / EE;
  int e = gid - l*EE;
  int src = ei[(2*l)*EE + e];
  int dst = ei[(2*l+1)*EE + e];
  int pos = atomicAdd(&cursor[l*NN+dst], 1);
  ssrc[pos]=src;
  sw[pos]=ew[gid];
}

__global__ void k_gather_emb(const int* __restrict__ verts, const float* __restrict__ emb,
                             float* __restrict__ x){
  int gid = blockIdx.x*256+threadIdx.x;   // over NN*32 float4s
  int n = gid>>5, q = gid&31;
  if (n>=NN) return;
  int v = verts[n];
  ((float4*)x)[gid] = ((const float4*)emb)[(size_t)v*32+q];
}

// ---------------- GEMM: Y[M,128] (+)= X[M,128] @ W[128,128] ----------------
// 64-row tile staged in LDS (33.8 KB, <=64KB limit); W streamed from L1/L2
// (all blocks read the same 64 KB, k-sequential). 256 thr, 4x8 micro-tile.
template<int ACC>
__global__ __launch_bounds__(256) void k_gemm128(const float* __restrict__ X,
    const float* __restrict__ W, float* __restrict__ Y, int M){
  __shared__ float Xs[64][132];           // [r][k], stride 132 (16B-aligned rows)
  int tid = threadIdx.x;
  int row0 = blockIdx.x*64;
  #pragma unroll
  for (int it=0; it<8; it++){
    int idx = tid + it*256;
    int r = idx>>5, kq = idx&31;
    float4 v = make_float4(0.f,0.f,0.f,0.f);
    if (row0+r < M) v = ((const float4*)X)[(size_t)(row0+r)*32 + kq];
    *(float4*)&Xs[r][kq*4] = v;
  }
  __syncthreads();
  int ty = tid>>4, tx = tid&15;           // rows ty*4..+3, cols tx*8..+7
  float acc[4][8];
  #pragma unroll
  for (int i=0;i<4;i++){
    #pragma unroll
    for (int j=0;j<8;j++) acc[i][j]=0.f;
  }
  const float* Wp = W + tx*8;
  #pragma unroll 8
  for (int k=0;k<128;k++){
    float4 w0 = *(const float4*)(Wp + k*128);
    float4 w1 = *(const float4*)(Wp + k*128 + 4);
    float xv[4];
    #pragma unroll
    for (int i=0;i<4;i++) xv[i]=Xs[ty*4+i][k];
    #pragma unroll
    for (int i=0;i<4;i++){
      acc[i][0]+=xv[i]*w0.x; acc[i][1]+=xv[i]*w0.y; acc[i][2]+=xv[i]*w0.z; acc[i][3]+=xv[i]*w0.w;
      acc[i][4]+=xv[i]*w1.x; acc[i][5]+=xv[i]*w1.y; acc[i][6]+=xv[i]*w1.z; acc[i][7]+=xv[i]*w1.w;
    }
  }
  #pragma unroll
  for (int i=0;i<4;i++){
    int r = row0 + ty*4 + i;
    if (r<M){
      float* yp = Y + (size_t)r*128 + tx*8;
      if (ACC){
        float4 y0 = *(float4*)yp, y1 = *(float4*)(yp+4);
        y0.x+=acc[i][0]; y0.y+=acc[i][1]; y0.z+=acc[i][2]; y0.w+=acc[i][3];
        y1.x+=acc[i][4]; y1.y+=acc[i][5]; y1.z+=acc[i][6]; y1.w+=acc[i][7];
        *(float4*)yp = y0; *(float4*)(yp+4) = y1;
      } else {
        float4 y0 = make_float4(acc[i][0],acc[i][1],acc[i][2],acc[i][3]);
        float4 y1 = make_float4(acc[i][4],acc[i][5],acc[i][6],acc[i][7]);
        *(float4*)yp = y0; *(float4*)(yp+4) = y1;
      }
    }
  }
}

// ---------------- Y[M,20] = X[M,128] @ W[128,20] ----------------
__global__ __launch_bounds__(256) void k_gemm_out(const float* __restrict__ X,
    const float* __restrict__ W, float* __restrict__ Y, int M){
  __shared__ float Ws[DIM*OUTC];
  __shared__ float Xs[8*DIM];
  int tid=threadIdx.x;
  for (int i=tid;i<DIM*OUTC;i+=256) Ws[i]=W[i];
  int row0=blockIdx.x*8;
  {
    int r = tid>>5, kq = tid&31;
    float4 v = make_float4(0.f,0.f,0.f,0.f);
    if (row0+r<M) v = ((const float4*)X)[(size_t)(row0+r)*32+kq];
    *(float4*)&Xs[r*DIM+kq*4]=v;
  }
  __syncthreads();
  int c = tid&31, rl=tid>>5;
  if (c<OUTC && row0+rl<M){
    float acc=0.f;
    #pragma unroll 8
    for (int k=0;k<DIM;k++) acc += Xs[rl*DIM+k]*Ws[k*OUTC+c];
    Y[(size_t)(row0+rl)*OUTC+c]=acc;
  }
}

// ---------------- SpMM gather: h[n] = sum_e w_e * sup[src_e] ----------------
__global__ __launch_bounds__(256) void k_spmm128(const float* __restrict__ sup,
    const int* __restrict__ ssrc, const float* __restrict__ sw,
    const int* __restrict__ offs, float* __restrict__ h, int base){
  int node = blockIdx.x*2 + (threadIdx.x>>7);
  int f = threadIdx.x & 127;
  int beg = offs[base+node], end = offs[base+node+1];
  float acc=0.f;
  for (int p=beg;p<end;p++){
    acc += sw[p] * sup[(size_t)ssrc[p]*DIM + f];
  }
  h[(size_t)node*DIM+f]=acc;
}

__global__ __launch_bounds__(256) void k_spmm_out(const float* __restrict__ sup,
    const int* __restrict__ ssrc, const float* __restrict__ sw,
    const int* __restrict__ offs, float* __restrict__ h, int base){
  int node = blockIdx.x*4 + (threadIdx.x>>6);
  int f = threadIdx.x & 63;
  if (f >= OUTC) return;
  int beg=offs[base+node], end=offs[base+node+1];
  float acc=0.f;
  for (int p=beg;p<end;p++){
    acc += sw[p]*sup[(size_t)ssrc[p]*OUTC+f];
  }
  h[(size_t)node*OUTC+f]=acc;
}

// ---------------- BatchNorm ----------------
template<int DP>
__global__ __launch_bounds__(256) void k_bn_stats(const float* __restrict__ h,
    int M, int D, float* __restrict__ gsum, float* __restrict__ gsumsq, int rpb){
  const int G = 256/DP;
  int f = threadIdx.x % DP;
  int g = threadIdx.x / DP;
  float s=0.f, ss=0.f;
  int r0 = blockIdx.x*rpb;
  int r1 = min(M, r0+rpb);
  if (f < D){
    for (int r=r0+g; r<r1; r+=G){ float v = h[(size_t)r*D+f]; s+=v; ss+=v*v; }
  }
  __shared__ float sh[256], sh2[256];
  sh[threadIdx.x]=s; sh2[threadIdx.x]=ss; __syncthreads();
  if (threadIdx.x < DP){
    #pragma unroll
    for (int i=1;i<G;i++){ s+=sh[threadIdx.x+i*DP]; ss+=sh2[threadIdx.x+i*DP]; }
    if (f<D){ atomicAdd(&gsum[f], s); atomicAdd(&gsumsq[f], ss); }
  }
}

// normalize + relu, D=128, vectorized float4 (bias cancels in BN -> omitted)
__global__ void k_bn_relu128(float* __restrict__ h, const float* __restrict__ gsum,
    const float* __restrict__ gsumsq, const float* __restrict__ gamma,
    const float* __restrict__ beta){
  int gid = blockIdx.x*256+threadIdx.x;  // NN*32
  if (gid >= NN*32) return;
  int fq = gid & 31;
  float4 s  = ((const float4*)gsum)[fq];
  float4 sq = ((const float4*)gsumsq)[fq];
  float4 ga = ((const float4*)gamma)[fq];
  float4 be = ((const float4*)beta)[fq];
  float4 v  = ((float4*)h)[gid];
  const float invN = 1.0f/NN;
  float m, var, sc;
  m=s.x*invN; var=sq.x*invN-m*m; sc=rsqrtf(var+BN_EPS)*ga.x; v.x=fmaxf((v.x-m)*sc+be.x,0.f);
  m=s.y*invN; var=sq.y*invN-m*m; sc=rsqrtf(var+BN_EPS)*ga.y; v.y=fmaxf((v.y-m)*sc+be.y,0.f);
  m=s.z*invN; var=sq.z*invN-m*m; sc=rsqrtf(var+BN_EPS)*ga.z; v.z=fmaxf((v.z-m)*sc+be.z,0.f);
  m=s.w*invN; var=sq.w*invN-m*m; sc=rsqrtf(var+BN_EPS)*ga.w; v.w=fmaxf((v.w-m)*sc+be.w,0.f);
  ((float4*)h)[gid]=v;
}

__global__ void k_bn_out(float* __restrict__ h, const float* __restrict__ gsum,
    const float* __restrict__ gsumsq, const float* __restrict__ gamma,
    const float* __restrict__ beta){
  int gid = blockIdx.x*256+threadIdx.x;
  if (gid>=NN*OUTC) return;
  int f = gid % OUTC;
  const float invN = 1.0f/NN;
  float m = gsum[f]*invN;
  float var = gsumsq[f]*invN - m*m;
  float sc = rsqrtf(var+BN_EPS)*gamma[f];
  h[gid] = fmaxf((h[gid]-m)*sc + beta[f], 0.f);   // fused post-loop relu
}

// ---------------- temporal gate: x = g*h + (1-g)*x ----------------
__global__ void k_gate(float* __restrict__ x, const float* __restrict__ h,
    const float* __restrict__ G, const float* __restrict__ teb){
  int gid = blockIdx.x*256+threadIdx.x;  // NN*32
  if (gid>=NN*32) return;
  int fq = gid&31;
  float4 b  = ((const float4*)teb)[fq];
  float4 gv = ((const float4*)G)[gid];
  float4 hv = ((const float4*)h)[gid];
  float4 xv = ((float4*)x)[gid];
  float g;
  g = sigm(gv.x+b.x); xv.x = g*hv.x + (1.f-g)*xv.x;
  g = sigm(gv.y+b.y); xv.y = g*hv.y + (1.f-g)*xv.y;
  g = sigm(gv.z+b.z); xv.z = g*hv.z + (1.f-g)*xv.z;
  g = sigm(gv.w+b.w); xv.w = g*hv.w + (1.f-g)*xv.w;
  ((float4*)x)[gid]=xv;
}

// ---------------- final masked reduce: acc[c] = sum_n mask_w[verts[n]] * xf[n][c] ----------------
__global__ __launch_bounds__(256) void k_reduce(const float* __restrict__ xf,
    const int* __restrict__ verts, const float* __restrict__ mw,
    float* __restrict__ acc, int rpb){
  int c = threadIdx.x & 31, g = threadIdx.x >> 5;
  int r0 = blockIdx.x*rpb;
  int r1 = min(NN, r0+rpb);
  float s=0.f;
  for (int r=r0+g; r<r1; r+=8){
    float m = mw[verts[r]];
    if (c<OUTC) s += m * xf[(size_t)r*OUTC+c];
  }
  __shared__ float sh[256];
  sh[threadIdx.x]=s; __syncthreads();
  if (threadIdx.x<32){
    #pragma unroll
    for (int i=1;i<8;i++) s += sh[threadIdx.x + i*32];
    if (c<OUTC) atomicAdd(&acc[c], s);
  }
}

__global__ void k_final(const float* __restrict__ acc, const float* __restrict__ mb,
                        float* __restrict__ out){
  int c=threadIdx.x;
  if (c<OUTC) out[c] = sigm(acc[c]+mb[c]);
}

// ---------------- host ----------------
extern "C" void kernel_launch(void* const* d_in, const int* in_sizes, int n_in,
                              void* d_out, int out_size, void* d_ws, size_t ws_size,
                              hipStream_t stream){
  const int*   verts = (const int*)d_in[0];
  const int*   ei    = (const int*)d_in[1];
  const float* ew    = (const float*)d_in[2];
  const float* emb   = (const float*)d_in[3];
  const float* wh    = (const float*)d_in[4];
  // d_in[5] gcn_b_hidden, d_in[7] gcn_b_out: cancel exactly under batchnorm
  const float* w_out = (const float*)d_in[6];
  const float* bng_h = (const float*)d_in[8];
  const float* bnb_h = (const float*)d_in[9];
  const float* bng_o = (const float*)d_in[10];
  const float* bnb_o = (const float*)d_in[11];
  const float* tewl  = (const float*)d_in[12];
  const float* tewc  = (const float*)d_in[13];
  const float* teb   = (const float*)d_in[14];
  const float* maskw = (const float*)d_in[15];
  const float* maskb = (const float*)d_in[16];
  float* out = (float*)d_out;

  char* ws = (char*)d_ws;
  size_t off=0;
  auto alloc=[&](size_t bytes)->char*{ char* p = ws+off; off += (bytes+255)&~(size_t)255; return p; };
  int*   ssrc   = (int*)  alloc(sizeof(int)*LE);          // 22.4 MB
  float* sw     = (float*)alloc(sizeof(float)*LE);        // 22.4 MB
  int*   offs   = (int*)  alloc(sizeof(int)*(LN+1));      // 1.4 MB
  int*   cursor = (int*)  alloc(sizeof(int)*LN);          // 1.4 MB (doubles as hist counts)
  int*   bsums  = (int*)  alloc(sizeof(int)*512);
  float* x      = (float*)alloc(sizeof(float)*NN*DIM);    // 25.6 MB
  float* bufB   = (float*)alloc(sizeof(float)*NN*DIM);    // 25.6 MB
  float* bufC   = (float*)alloc(sizeof(float)*NN*DIM);    // 25.6 MB
  float* stats  = (float*)alloc(sizeof(float)*288);
  float* gsum=stats; float* gsumsq=stats+128; float* racc=stats+256;

  // --- sort all 7 edge lists by dst (global scan over concatenated counts:
  //     layer l occupies [l*EE,(l+1)*EE) of the sorted arrays automatically) ---
  hipMemsetAsync(cursor, 0, sizeof(int)*LN, stream);
  k_hist<<<(LE+255)/256,256,0,stream>>>(ei, cursor);
  int nsb = (LN+1023)/1024;  // 342
  k_scan1<<<nsb,256,0,stream>>>(cursor, offs, bsums, LN);
  k_scan2<<<1,512,0,stream>>>(bsums, nsb);
  k_scan3<<<(LN+255)/256,256,0,stream>>>(offs, bsums, cursor, LN);
  k_scatter<<<(LE+255)/256,256,0,stream>>>(ei, ew, cursor, ssrc, sw);
  k_gather_emb<<<NN*32/256,256,0,stream>>>(verts, emb, x);

  // --- 6 hidden layers ---
  for (int i=0;i<6;i++){
    int j = (i==0)?5:(i-1);   // (i-1) % 6, Python semantics
    k_gemm128<0><<<(NN+63)/64,256,0,stream>>>(x, wh + (size_t)i*DIM*DIM, bufB, NN);
    k_spmm128<<<NN/2,256,0,stream>>>(bufB, ssrc, sw, offs, bufC, i*NN);
    hipMemsetAsync(stats, 0, 1024, stream);
    k_bn_stats<128><<<512,256,0,stream>>>(bufC, NN, DIM, gsum, gsumsq, 98);
    k_bn_relu128<<<NN*32/256,256,0,stream>>>(bufC, gsum, gsumsq, bng_h+(size_t)i*DIM, bnb_h+(size_t)i*DIM);
    k_gemm128<0><<<(NN+63)/64,256,0,stream>>>(x,    tewl + (size_t)j*DIM*DIM, bufB, NN);
    k_gemm128<1><<<(NN+63)/64,256,0,stream>>>(bufC, tewc + (size_t)j*DIM*DIM, bufB, NN);
    k_gate<<<NN*32/256,256,0,stream>>>(x, bufC, bufB, teb + (size_t)j*DIM);
  }

  // --- output layer ---
  k_gemm_out<<<(NN+7)/8,256,0,stream>>>(x, w_out, bufB, NN);
  k_spmm_out<<<NN/4,256,0,stream>>>(bufB, ssrc, sw, offs, bufC, 6*NN);
  hipMemsetAsync(stats, 0, 1024, stream);
  k_bn_stats<32><<<512,256,0,stream>>>(bufC, NN, OUTC, gsum, gsumsq, 98);
  k_bn_out<<<(NN*OUTC+255)/256,256,0,stream>>>(bufC, gsum, gsumsq, bng_o, bnb_o);
  hipMemsetAsync(racc, 0, sizeof(float)*32, stream);
  k_reduce<<<512,256,0,stream>>>(bufC, verts, maskw, racc, 98);
  k_final<<<1,64,0,stream>>>(racc, maskb, out);
}

// Round 2
// 2331.478 us; speedup vs baseline: 1.1688x; 1.1688x over previous
//
#include <hip/hip_runtime.h>

#define NN 50000
#define EE 800000
#define DIM 128
#define OUTC 20
#define LL 7
#define LE (LL*EE)
#define LN (LL*NN)
#define BN_EPS 1e-5f

static __device__ __forceinline__ float sigm(float z){ return 1.0f/(1.0f+expf(-z)); }

// ---------------- preprocessing: counting sort of all 7 edge lists by dst ----------------
__global__ void k_hist(const int* __restrict__ ei, int* __restrict__ cnt){
  int gid = blockIdx.x*256 + threadIdx.x;
  if (gid >= LE) return;
  int l = gid / EE;
  int e = gid - l*EE;
  int dst = ei[(2*l+1)*EE + e];
  atomicAdd(&cnt[l*NN + dst], 1);
}

__global__ void k_scan1(const int* __restrict__ cnt, int* __restrict__ offs,
                        int* __restrict__ bsums, int n){
  __shared__ int s[256];
  int t = threadIdx.x;
  int base = blockIdx.x*1024 + t*4;
  int v[4]; int sum = 0;
  #pragma unroll
  for (int i=0;i<4;i++){ v[i] = (base+i<n)? cnt[base+i] : 0; sum += v[i]; }
  s[t]=sum; __syncthreads();
  for (int off=1; off<256; off<<=1){
    int x = (t>=off)? s[t-off] : 0;
    __syncthreads();
    s[t] += x;
    __syncthreads();
  }
  if (t==255) bsums[blockIdx.x] = s[255];
  int run = s[t]-sum;
  #pragma unroll
  for (int i=0;i<4;i++){ if (base+i<n) offs[base+i]=run; run += v[i]; }
}

__global__ void k_scan2(int* bsums, int nb){
  __shared__ int s[512];
  int t=threadIdx.x;
  int v = (t<nb)? bsums[t]:0;
  s[t]=v; __syncthreads();
  for (int off=1; off<512; off<<=1){
    int x=(t>=off)? s[t-off]:0; __syncthreads(); s[t]+=x; __syncthreads();
  }
  if (t<nb) bsums[t] = s[t]-v;
}

__global__ void k_scan3(int* __restrict__ offs, const int* __restrict__ bsums,
                        int* __restrict__ cursor, int n){
  int gid = blockIdx.x*256+threadIdx.x;
  if (gid < n){
    int val = offs[gid] + bsums[gid>>10];
    offs[gid]=val; cursor[gid]=val;
  }
  if (gid==0) offs[n]=LE;
}

// packed scatter: one random 8B write per edge (src + weight bits in one int2)
__global__ void k_scatter(const int* __restrict__ ei, const float* __restrict__ ew,
                          int* __restrict__ cursor, int2* __restrict__ sedge){
  int gid = blockIdx.x*256+threadIdx.x;
  if (gid>=LE) return;
  int l = gid / EE;
  int e = gid - l*EE;
  int src = ei[(2*l)*EE + e];
  int dst = ei[(2*l+1)*EE + e];
  int pos = atomicAdd(&cursor[l*NN+dst], 1);
  sedge[pos] = make_int2(src, __float_as_int(ew[gid]));
}

__global__ void k_gather_emb(const int* __restrict__ verts, const float* __restrict__ emb,
                             float* __restrict__ x){
  int gid = blockIdx.x*256+threadIdx.x;   // over NN*32 float4s
  int n = gid>>5, q = gid&31;
  if (n>=NN) return;
  int v = verts[n];
  ((float4*)x)[gid] = ((const float4*)emb)[(size_t)v*32+q];
}

// ---------------- GEMM: Y[M,128] = X[M,128] @ W[128,128] ----------------
// X tile transposed in LDS (XsT[k][r], stride 68 -> 16B aligned rows, bank-spread);
// per-k fragment is ONE ds_read_b128. W streamed from L1 (same-address lanes dedup).
#define XS_STRIDE 68
__global__ __launch_bounds__(256) void k_gemm128v(const float* __restrict__ X,
    const float* __restrict__ W, float* __restrict__ Y, int M){
  __shared__ float Xs[128*XS_STRIDE];     // 34 KB
  int tid = threadIdx.x;
  int row0 = blockIdx.x*64;
  #pragma unroll
  for (int it=0; it<8; it++){
    int idx = tid + it*256;
    int r = idx>>5, kq = idx&31;
    float4 v = make_float4(0.f,0.f,0.f,0.f);
    if (row0+r < M) v = ((const float4*)X)[(size_t)(row0+r)*32 + kq];
    Xs[(kq*4+0)*XS_STRIDE+r]=v.x; Xs[(kq*4+1)*XS_STRIDE+r]=v.y;
    Xs[(kq*4+2)*XS_STRIDE+r]=v.z; Xs[(kq*4+3)*XS_STRIDE+r]=v.w;
  }
  __syncthreads();
  int ty = tid>>4, tx = tid&15;           // rows ty*4..+3, cols tx*8..+7
  float acc[4][8];
  #pragma unroll
  for (int i=0;i<4;i++){
    #pragma unroll
    for (int j=0;j<8;j++) acc[i][j]=0.f;
  }
  const float* Wp = W + tx*8;
  #pragma unroll 4
  for (int k=0;k<128;k++){
    float4 xv = *(const float4*)&Xs[k*XS_STRIDE + ty*4];
    float4 w0 = *(const float4*)(Wp + k*128);
    float4 w1 = *(const float4*)(Wp + k*128 + 4);
    float xr[4] = {xv.x, xv.y, xv.z, xv.w};
    #pragma unroll
    for (int i=0;i<4;i++){
      acc[i][0]+=xr[i]*w0.x; acc[i][1]+=xr[i]*w0.y; acc[i][2]+=xr[i]*w0.z; acc[i][3]+=xr[i]*w0.w;
      acc[i][4]+=xr[i]*w1.x; acc[i][5]+=xr[i]*w1.y; acc[i][6]+=xr[i]*w1.z; acc[i][7]+=xr[i]*w1.w;
    }
  }
  #pragma unroll
  for (int i=0;i<4;i++){
    int r = row0 + ty*4 + i;
    if (r<M){
      float* yp = Y + (size_t)r*128 + tx*8;
      *(float4*)yp     = make_float4(acc[i][0],acc[i][1],acc[i][2],acc[i][3]);
      *(float4*)(yp+4) = make_float4(acc[i][4],acc[i][5],acc[i][6],acc[i][7]);
    }
  }
}

// ---------------- fused: BN(h)+ReLU during staging, GEMM (hn @ te_wc), gate epilogue ----------------
// x_new = g*hn + (1-g)*x_old,  g = sigmoid(hn@te_wc + D + teb),  D = x_old@te_wl (bufB)
__global__ __launch_bounds__(256) void k_gemm_gate(const float* __restrict__ H,
    const float* __restrict__ W, const float* __restrict__ D,
    const float* __restrict__ teb,
    const float* __restrict__ gsum, const float* __restrict__ gsumsq,
    const float* __restrict__ gamma, const float* __restrict__ beta,
    float* __restrict__ x, int M){
  __shared__ float Xs[128*XS_STRIDE];
  int tid = threadIdx.x;
  int row0 = blockIdx.x*64;
  const float invN = 1.0f/NN;
  #pragma unroll
  for (int it=0; it<8; it++){
    int idx = tid + it*256;
    int r = idx>>5, kq = idx&31;
    float4 v = make_float4(0.f,0.f,0.f,0.f);
    if (row0+r < M) v = ((const float4*)H)[(size_t)(row0+r)*32 + kq];
    float4 s  = ((const float4*)gsum)[kq];
    float4 sq = ((const float4*)gsumsq)[kq];
    float4 ga = ((const float4*)gamma)[kq];
    float4 be = ((const float4*)beta)[kq];
    float m, var, sc;
    m=s.x*invN; var=sq.x*invN-m*m; sc=rsqrtf(var+BN_EPS)*ga.x; v.x=fmaxf((v.x-m)*sc+be.x,0.f);
    m=s.y*invN; var=sq.y*invN-m*m; sc=rsqrtf(var+BN_EPS)*ga.y; v.y=fmaxf((v.y-m)*sc+be.y,0.f);
    m=s.z*invN; var=sq.z*invN-m*m; sc=rsqrtf(var+BN_EPS)*ga.z; v.z=fmaxf((v.z-m)*sc+be.z,0.f);
    m=s.w*invN; var=sq.w*invN-m*m; sc=rsqrtf(var+BN_EPS)*ga.w; v.w=fmaxf((v.w-m)*sc+be.w,0.f);
    Xs[(kq*4+0)*XS_STRIDE+r]=v.x; Xs[(kq*4+1)*XS_STRIDE+r]=v.y;
    Xs[(kq*4+2)*XS_STRIDE+r]=v.z; Xs[(kq*4+3)*XS_STRIDE+r]=v.w;
  }
  __syncthreads();
  int ty = tid>>4, tx = tid&15;
  float acc[4][8];
  #pragma unroll
  for (int i=0;i<4;i++){
    #pragma unroll
    for (int j=0;j<8;j++) acc[i][j]=0.f;
  }
  const float* Wp = W + tx*8;
  #pragma unroll 4
  for (int k=0;k<128;k++){
    float4 xv = *(const float4*)&Xs[k*XS_STRIDE + ty*4];
    float4 w0 = *(const float4*)(Wp + k*128);
    float4 w1 = *(const float4*)(Wp + k*128 + 4);
    float xr[4] = {xv.x, xv.y, xv.z, xv.w};
    #pragma unroll
    for (int i=0;i<4;i++){
      acc[i][0]+=xr[i]*w0.x; acc[i][1]+=xr[i]*w0.y; acc[i][2]+=xr[i]*w0.z; acc[i][3]+=xr[i]*w0.w;
      acc[i][4]+=xr[i]*w1.x; acc[i][5]+=xr[i]*w1.y; acc[i][6]+=xr[i]*w1.z; acc[i][7]+=xr[i]*w1.w;
    }
  }
  // gate epilogue: hn for this thread's 4x8 patch comes straight from LDS
  float4 b0 = ((const float4*)teb)[tx*2];
  float4 b1 = ((const float4*)teb)[tx*2+1];
  float hcol[8][4];     // hcol[j][i] = hn[row ty*4+i][col tx*8+j]
  #pragma unroll
  for (int j=0;j<8;j++){
    float4 hv = *(const float4*)&Xs[(tx*8+j)*XS_STRIDE + ty*4];
    hcol[j][0]=hv.x; hcol[j][1]=hv.y; hcol[j][2]=hv.z; hcol[j][3]=hv.w;
  }
  #pragma unroll
  for (int i=0;i<4;i++){
    int r = row0 + ty*4 + i;
    if (r<M){
      const float* dp = D + (size_t)r*128 + tx*8;
      float* xp = x + (size_t)r*128 + tx*8;
      float4 d0 = *(const float4*)dp, d1 = *(const float4*)(dp+4);
      float4 xo0 = *(const float4*)xp, xo1 = *(const float4*)(xp+4);
      float g;
      float4 n0, n1;
      g=sigm(acc[i][0]+d0.x+b0.x); n0.x = g*hcol[0][i] + (1.f-g)*xo0.x;
      g=sigm(acc[i][1]+d0.y+b0.y); n0.y = g*hcol[1][i] + (1.f-g)*xo0.y;
      g=sigm(acc[i][2]+d0.z+b0.z); n0.z = g*hcol[2][i] + (1.f-g)*xo0.z;
      g=sigm(acc[i][3]+d0.w+b0.w); n0.w = g*hcol[3][i] + (1.f-g)*xo0.w;
      g=sigm(acc[i][4]+d1.x+b1.x); n1.x = g*hcol[4][i] + (1.f-g)*xo1.x;
      g=sigm(acc[i][5]+d1.y+b1.y); n1.y = g*hcol[5][i] + (1.f-g)*xo1.y;
      g=sigm(acc[i][6]+d1.z+b1.z); n1.z = g*hcol[6][i] + (1.f-g)*xo1.z;
      g=sigm(acc[i][7]+d1.w+b1.w); n1.w = g*hcol[7][i] + (1.f-g)*xo1.w;
      *(float4*)xp = n0; *(float4*)(xp+4) = n1;
    }
  }
}

// ---------------- Y[M,20] = X[M,128] @ W[128,20] ----------------
__global__ __launch_bounds__(256) void k_gemm_out(const float* __restrict__ X,
    const float* __restrict__ W, float* __restrict__ Y, int M){
  __shared__ float Ws[DIM*OUTC];
  __shared__ float Xs2[8*DIM];
  int tid=threadIdx.x;
  for (int i=tid;i<DIM*OUTC;i+=256) Ws[i]=W[i];
  int row0=blockIdx.x*8;
  {
    int r = tid>>5, kq = tid&31;
    float4 v = make_float4(0.f,0.f,0.f,0.f);
    if (row0+r<M) v = ((const float4*)X)[(size_t)(row0+r)*32+kq];
    *(float4*)&Xs2[r*DIM+kq*4]=v;
  }
  __syncthreads();
  int c = tid&31, rl=tid>>5;
  if (c<OUTC && row0+rl<M){
    float acc=0.f;
    #pragma unroll 8
    for (int k=0;k<DIM;k++) acc += Xs2[rl*DIM+k]*Ws[k*OUTC+c];
    Y[(size_t)(row0+rl)*OUTC+c]=acc;
  }
}

// ---------------- SpMM gather: h[n] = sum_e w_e * sup[src_e] ----------------
__global__ __launch_bounds__(256) void k_spmm128(const float* __restrict__ sup,
    const int2* __restrict__ sedge, const int* __restrict__ offs,
    float* __restrict__ h, int base){
  int node = blockIdx.x*2 + (threadIdx.x>>7);
  int f = threadIdx.x & 127;
  int beg = offs[base+node], end = offs[base+node+1];
  float acc=0.f, acc2=0.f;
  int p=beg;
  for (; p+1<end; p+=2){
    int2 e0 = sedge[p], e1 = sedge[p+1];
    acc  += __int_as_float(e0.y) * sup[(size_t)e0.x*DIM + f];
    acc2 += __int_as_float(e1.y) * sup[(size_t)e1.x*DIM + f];
  }
  if (p<end){
    int2 e0 = sedge[p];
    acc += __int_as_float(e0.y) * sup[(size_t)e0.x*DIM + f];
  }
  h[(size_t)node*DIM+f]=acc+acc2;
}

__global__ __launch_bounds__(256) void k_spmm_out(const float* __restrict__ sup,
    const int2* __restrict__ sedge, const int* __restrict__ offs,
    float* __restrict__ h, int base){
  int node = blockIdx.x*4 + (threadIdx.x>>6);
  int f = threadIdx.x & 63;
  if (f >= OUTC) return;
  int beg=offs[base+node], end=offs[base+node+1];
  float acc=0.f;
  for (int p=beg;p<end;p++){
    int2 e = sedge[p];
    acc += __int_as_float(e.y)*sup[(size_t)e.x*OUTC+f];
  }
  h[(size_t)node*OUTC+f]=acc;
}

// ---------------- BatchNorm stats ----------------
template<int DP>
__global__ __launch_bounds__(256) void k_bn_stats(const float* __restrict__ h,
    int M, int D, float* __restrict__ gsum, float* __restrict__ gsumsq, int rpb){
  const int G = 256/DP;
  int f = threadIdx.x % DP;
  int g = threadIdx.x / DP;
  float s=0.f, ss=0.f;
  int r0 = blockIdx.x*rpb;
  int r1 = min(M, r0+rpb);
  if (f < D){
    for (int r=r0+g; r<r1; r+=G){ float v = h[(size_t)r*D+f]; s+=v; ss+=v*v; }
  }
  __shared__ float sh[256], sh2[256];
  sh[threadIdx.x]=s; sh2[threadIdx.x]=ss; __syncthreads();
  if (threadIdx.x < DP){
    #pragma unroll
    for (int i=1;i<G;i++){ s+=sh[threadIdx.x+i*DP]; ss+=sh2[threadIdx.x+i*DP]; }
    if (f<D){ atomicAdd(&gsum[f], s); atomicAdd(&gsumsq[f], ss); }
  }
}

__global__ void k_bn_out(float* __restrict__ h, const float* __restrict__ gsum,
    const float* __restrict__ gsumsq, const float* __restrict__ gamma,
    const float* __restrict__ beta){
  int gid = blockIdx.x*256+threadIdx.x;
  if (gid>=NN*OUTC) return;
  int f = gid % OUTC;
  const float invN = 1.0f/NN;
  float m = gsum[f]*invN;
  float var = gsumsq[f]*invN - m*m;
  float sc = rsqrtf(var+BN_EPS)*gamma[f];
  h[gid] = fmaxf((h[gid]-m)*sc + beta[f], 0.f);   // fused post-loop relu
}

// ---------------- final masked reduce ----------------
__global__ __launch_bounds__(256) void k_reduce(const float* __restrict__ xf,
    const int* __restrict__ verts, const float* __restrict__ mw,
    float* __restrict__ acc, int rpb){
  int c = threadIdx.x & 31, g = threadIdx.x >> 5;
  int r0 = blockIdx.x*rpb;
  int r1 = min(NN, r0+rpb);
  float s=0.f;
  for (int r=r0+g; r<r1; r+=8){
    float m = mw[verts[r]];
    if (c<OUTC) s += m * xf[(size_t)r*OUTC+c];
  }
  __shared__ float sh[256];
  sh[threadIdx.x]=s; __syncthreads();
  if (threadIdx.x<32){
    #pragma unroll
    for (int i=1;i<8;i++) s += sh[threadIdx.x + i*32];
    if (c<OUTC) atomicAdd(&acc[c], s);
  }
}

__global__ void k_final(const float* __restrict__ acc, const float* __restrict__ mb,
                        float* __restrict__ out){
  int c=threadIdx.x;
  if (c<OUTC) out[c] = sigm(acc[c]+mb[c]);
}

// ---------------- host ----------------
extern "C" void kernel_launch(void* const* d_in, const int* in_sizes, int n_in,
                              void* d_out, int out_size, void* d_ws, size_t ws_size,
                              hipStream_t stream){
  const int*   verts = (const int*)d_in[0];
  const int*   ei    = (const int*)d_in[1];
  const float* ew    = (const float*)d_in[2];
  const float* emb   = (const float*)d_in[3];
  const float* wh    = (const float*)d_in[4];
  // d_in[5] gcn_b_hidden, d_in[7] gcn_b_out: cancel exactly under batchnorm
  const float* w_out = (const float*)d_in[6];
  const float* bng_h = (const float*)d_in[8];
  const float* bnb_h = (const float*)d_in[9];
  const float* bng_o = (const float*)d_in[10];
  const float* bnb_o = (const float*)d_in[11];
  const float* tewl  = (const float*)d_in[12];
  const float* tewc  = (const float*)d_in[13];
  const float* teb   = (const float*)d_in[14];
  const float* maskw = (const float*)d_in[15];
  const float* maskb = (const float*)d_in[16];
  float* out = (float*)d_out;

  char* ws = (char*)d_ws;
  size_t off=0;
  auto alloc=[&](size_t bytes)->char*{ char* p = ws+off; off += (bytes+255)&~(size_t)255; return p; };
  int2*  sedge  = (int2*) alloc(sizeof(int2)*LE);         // 44.8 MB
  int*   offs   = (int*)  alloc(sizeof(int)*(LN+1));      // 1.4 MB
  int*   cursor = (int*)  alloc(sizeof(int)*LN);          // 1.4 MB (doubles as hist counts)
  int*   bsums  = (int*)  alloc(sizeof(int)*512);
  float* x      = (float*)alloc(sizeof(float)*NN*DIM);    // 25.6 MB
  float* bufB   = (float*)alloc(sizeof(float)*NN*DIM);    // 25.6 MB
  float* bufC   = (float*)alloc(sizeof(float)*NN*DIM);    // 25.6 MB
  float* stats  = (float*)alloc(sizeof(float)*(LL*256+32)); // per-layer gsum/gsumsq + racc
  float* racc   = stats + LL*256;

  // --- sort all 7 edge lists by dst ---
  hipMemsetAsync(cursor, 0, sizeof(int)*LN, stream);
  hipMemsetAsync(stats, 0, sizeof(float)*(LL*256+32), stream);
  k_hist<<<(LE+255)/256,256,0,stream>>>(ei, cursor);
  int nsb = (LN+1023)/1024;  // 342
  k_scan1<<<nsb,256,0,stream>>>(cursor, offs, bsums, LN);
  k_scan2<<<1,512,0,stream>>>(bsums, nsb);
  k_scan3<<<(LN+255)/256,256,0,stream>>>(offs, bsums, cursor, LN);
  k_scatter<<<(LE+255)/256,256,0,stream>>>(ei, ew, cursor, sedge);
  k_gather_emb<<<NN*32/256,256,0,stream>>>(verts, emb, x);

  // --- 6 hidden layers ---
  for (int i=0;i<6;i++){
    int j = (i==0)?5:(i-1);   // (i-1) % 6, Python semantics
    float* gsum = stats + i*256, *gsumsq = gsum + 128;
    k_gemm128v<<<(NN+63)/64,256,0,stream>>>(x, wh + (size_t)i*DIM*DIM, bufB, NN);
    k_spmm128<<<NN/2,256,0,stream>>>(bufB, sedge, offs, bufC, i*NN);
    k_bn_stats<128><<<512,256,0,stream>>>(bufC, NN, DIM, gsum, gsumsq, 98);
    k_gemm128v<<<(NN+63)/64,256,0,stream>>>(x, tewl + (size_t)j*DIM*DIM, bufB, NN);
    k_gemm_gate<<<(NN+63)/64,256,0,stream>>>(bufC, tewc + (size_t)j*DIM*DIM, bufB,
        teb + (size_t)j*DIM, gsum, gsumsq,
        bng_h+(size_t)i*DIM, bnb_h+(size_t)i*DIM, x, NN);
  }

  // --- output layer ---
  float* gsum = stats + 6*256, *gsumsq = gsum + 128;
  k_gemm_out<<<(NN+7)/8,256,0,stream>>>(x, w_out, bufB, NN);
  k_spmm_out<<<NN/4,256,0,stream>>>(bufB, sedge, offs, bufC, 6*NN);
  k_bn_stats<32><<<512,256,0,stream>>>(bufC, NN, OUTC, gsum, gsumsq, 98);
  k_bn_out<<<(NN*OUTC+255)/256,256,0,stream>>>(bufC, gsum, gsumsq, bng_o, bnb_o);
  k_reduce<<<512,256,0,stream>>>(bufC, verts, maskw, racc, 98);
  k_final<<<1,64,0,stream>>>(racc, maskb, out);
}